// Round 7
// baseline (487.566 us; speedup 1.0000x reference)
//
#include <hip/hip_runtime.h>

// x: [8, 32, 32, 32, 32] fp32.  Flat = b*2^20 + i*32768 + j*1024 + k*32 + c
// W: [32, 256] row-major (o, 8 sections). Sections:
//   0:x 1:mean_i 2:mean_j 3:mean_k 4:mean_ij 5:mean_ik 6:mean_jk 7:mean_ijk
// out[b,i,j,k,o] = W0.x + B1[b,j,k,o] + B2[b,i,k,o] + A3[b,i,j,o]
//                + A12[b,k,o] + A13[b,j,o] + A23[b,i,o] + A123[b,o] + bias[o]
// R13: R12's 3-phase fusion, but WITHOUT hipLaunchCooperativeKernel (R12's
// coop launch never executed under graph capture -> zero output). Plain
// launch, manual grid barrier: device-scope atomic counter (memset on the
// stream pre-launch), release = threadfence+syncthreads before add, acquire
// = spin + syncthreads + threadfence after. Co-residency by construction:
// LDS 32.9KB -> 4 blocks/CU capacity, grid 768 = 3/CU. Phase bodies are
// verbatim from verified kernels (P1 = R4 reduce, P2 = R5 slim mid,
// P3 = R4 staged final, grid-strided).

static __device__ __forceinline__ float4 f4add(float4 a, float4 b) {
  a.x += b.x; a.y += b.y; a.z += b.z; a.w += b.w; return a;
}

static __device__ __forceinline__ void grid_barrier(unsigned* cnt, unsigned target) {
  __threadfence();                 // release: each thread's writes -> device scope
  __syncthreads();                 // all threads of block fenced
  if (threadIdx.x == 0) {
    __hip_atomic_fetch_add(cnt, 1u, __ATOMIC_RELEASE, __HIP_MEMORY_SCOPE_AGENT);
    while (__hip_atomic_load(cnt, __ATOMIC_ACQUIRE, __HIP_MEMORY_SCOPE_AGENT) < target)
      __builtin_amdgcn_s_sleep(8);
  }
  __syncthreads();
  __threadfence();                 // acquire: invalidate stale cached lines
}

__global__ __launch_bounds__(256) void fused_kernel(
    const float* __restrict__ x, const float* __restrict__ W,
    const float* __restrict__ bias,
    float* __restrict__ S1, float* __restrict__ S2, float* __restrict__ S3,
    float* __restrict__ B1, float* __restrict__ B2, float* __restrict__ A3o,
    float* __restrict__ A12g, float* __restrict__ A13g,
    float* __restrict__ A23g, float* __restrict__ A123g,
    float* __restrict__ W0t, unsigned* __restrict__ barrier_cnt,
    float* __restrict__ out) {
  __shared__ float smem[8224];   // P1 segA: 8*1028. P2: <=4096. P3: 5248.
  const int t = threadIdx.x;
  const int bid = blockIdx.x;

  // ---------------- Phase 1: first-level reductions (512 units) -----------
  if (bid < 256) {
    // seg0: S1[b, j=a, k, c] = sum_i x[b,i,a,k,c]
    const int b = bid >> 5, a = bid & 31;
    const float* base = x + ((size_t)b << 20) + a * 1024 + 4 * t;
    float4 acc = make_float4(0.f, 0.f, 0.f, 0.f);
    #pragma unroll
    for (int i = 0; i < 32; ++i) acc = f4add(acc, *(const float4*)(base + i * 32768));
    ((float4*)(S1 + (size_t)(b * 32 + a) * 1024))[t] = acc;
  } else if (bid < 512) {
    // segA: block (b, i=a): stream slab x[b,a,:,:,:] once -> S2 row + S3 row
    float* sT = smem;                        // [8][1028]
    const int idx = bid - 256;
    const int b = idx >> 5, a = idx & 31;
    const float* slab = x + ((size_t)b << 20) + a * 32768;
    float4 accS2 = make_float4(0.f, 0.f, 0.f, 0.f);
    const int jl = t >> 5, cc = t & 31;      // S3 role: (j_loc, c)
    float* s3row = S3 + (size_t)(b * 32 + a) * 1024;

    for (int jt = 0; jt < 4; ++jt) {
      const float4* src4 = (const float4*)(slab + jt * 8192);
      #pragma unroll
      for (int m = 0; m < 8; ++m) {
        const int q = t + 256 * m;           // float4 idx in tile
        const float4 v = src4[q];
        float* p = sT + (q >> 8) * 1028 + 4 * (q & 255);
        p[0] = v.x; p[1] = v.y; p[2] = v.z; p[3] = v.w;
      }
      __syncthreads();
      #pragma unroll
      for (int j = 0; j < 8; ++j)
        accS2 = f4add(accS2, *(const float4*)(sT + j * 1028 + 4 * t));
      float s3 = 0.f;
      #pragma unroll
      for (int k = 0; k < 32; ++k) s3 += sT[jl * 1028 + k * 32 + cc];
      s3row[jt * 256 + t] = s3;              // j = 8*jt + jl, coalesced
      __syncthreads();
    }
    ((float4*)(S2 + (size_t)(b * 32 + a) * 1024))[t] = accS2;
  }

  grid_barrier(barrier_cnt, 768);

  // ---------------- Phase 2: projections + second-level pools --------------
  if (bid < 192) {
    // three [8192x32]x[32x32] GEMMs, 128 rows/block, x read global->reg
    float* wt = smem;            // W section seg+1 transposed [c*32+o]
    const int seg = bid / 64;
    const int r0 = (bid & 63) * 128;
    const float* src = (seg == 0) ? S1 : (seg == 1) ? S2 : S3;
    float* dst = (seg == 0) ? B1 : (seg == 1) ? B2 : A3o;

    #pragma unroll
    for (int m = 0; m < 4; ++m) {
      const int e = t + 256 * m;
      wt[e] = W[(e & 31) * 256 + (seg + 1) * 32 + (e >> 5)];
    }
    if (bid == 0) {
      #pragma unroll
      for (int m = 0; m < 4; ++m) {
        const int e = t + 256 * m;
        W0t[e] = W[(e & 31) * 256 + (e >> 5)];   // W0t[c*32+o]
      }
    }
    __syncthreads();

    const int rg = t >> 3, og = t & 7;
    const int row0 = r0 + 4 * rg;
    const int oo = og * 4;
    float acc[4][4];
    #pragma unroll
    for (int r = 0; r < 4; ++r)
      #pragma unroll
      for (int u = 0; u < 4; ++u) acc[r][u] = 0.f;

    const float4* wt4 = (const float4*)wt;
    const float4* sr4 = (const float4*)(src + (size_t)row0 * 32);
    #pragma unroll
    for (int cb = 0; cb < 4; ++cb) {
      float xv[4][8];
      #pragma unroll
      for (int r = 0; r < 4; ++r) {
        const float4 a0 = sr4[r * 8 + cb * 2];
        const float4 a1 = sr4[r * 8 + cb * 2 + 1];
        xv[r][0] = a0.x; xv[r][1] = a0.y; xv[r][2] = a0.z; xv[r][3] = a0.w;
        xv[r][4] = a1.x; xv[r][5] = a1.y; xv[r][6] = a1.z; xv[r][7] = a1.w;
      }
      #pragma unroll
      for (int cc = 0; cc < 8; ++cc) {
        const float4 w = wt4[(cb * 8 + cc) * 8 + og];
        #pragma unroll
        for (int r = 0; r < 4; ++r) {
          acc[r][0] += xv[r][cc] * w.x; acc[r][1] += xv[r][cc] * w.y;
          acc[r][2] += xv[r][cc] * w.z; acc[r][3] += xv[r][cc] * w.w;
        }
      }
    }
    const float s = 1.f / 32.f;
    #pragma unroll
    for (int r = 0; r < 4; ++r) {
      *(float4*)(dst + (size_t)(row0 + r) * 32 + oo) =
          make_float4(acc[r][0] * s, acc[r][1] * s, acc[r][2] * s, acc[r][3] * s);
    }
  } else if (bid < 216) {
    // pool: blk = seg*8 + b
    const int blk = bid - 192;
    const int seg = blk >> 3, b = blk & 7;
    float* sBuf  = smem;          // [32][32] second-level sums
    float* sW    = smem + 1024;   // section 4+seg transposed [c*32+o]
    float* sW7   = smem + 2048;   // section 7 transposed
    float* sS123 = smem + 3072;   // [32]
    const int sec = 4 + seg;

    #pragma unroll
    for (int m = 0; m < 4; ++m) {
      const int e = t + 256 * m, c = e >> 5, o = e & 31;
      sW[e] = W[o * 256 + sec * 32 + c];
      if (seg == 0) sW7[e] = W[o * 256 + 7 * 32 + c];
    }
    const float* Sb = ((seg == 2) ? S2 : S1) + (size_t)b * 32768;
    #pragma unroll
    for (int m = 0; m < 4; ++m) {
      const int e = t + 256 * m, a = e >> 5, c = e & 31;
      float s = 0.f;
      if (seg == 0) {            // S12[k=a,c] = sum_j S1[b,j,a,c]
        for (int j = 0; j < 32; ++j) s += Sb[j * 1024 + a * 32 + c];
      } else {                   // S13/S23[(j|i)=a,c] = sum_k
        for (int k = 0; k < 32; ++k) s += Sb[a * 1024 + k * 32 + c];
      }
      sBuf[e] = s;
    }
    __syncthreads();
    if (seg == 0 && t < 32) {
      float s = 0.f;
      for (int k = 0; k < 32; ++k) s += sBuf[k * 32 + t];
      sS123[t] = s;
    }
    __syncthreads();
    float* Ag = (seg == 0) ? A12g : (seg == 1) ? A13g : A23g;
    #pragma unroll
    for (int m = 0; m < 4; ++m) {
      const int e = t + 256 * m, a = e >> 5, o = e & 31;
      float s = 0.f;
      #pragma unroll
      for (int c = 0; c < 32; ++c) s += sW[c * 32 + o] * sBuf[a * 32 + c];
      Ag[b * 1024 + e] = s * (1.f / 1024.f);
    }
    if (seg == 0 && t < 32) {
      float s = 0.f;
      #pragma unroll
      for (int c = 0; c < 32; ++c) s += sW7[c * 32 + t] * sS123[c];
      A123g[b * 32 + t] = s * (1.f / 32768.f);
    }
  }

  grid_barrier(barrier_cnt, 1536);

  // ---------------- Phase 3: final combine (2048 tiles, grid-strided) ------
  {
    float* xs = smem;            // [128][33]
    float* wt = smem + 4224;     // W0 transposed [c*32+o]
    const int rg = t >> 3, og = t & 7;
    const int lrow0 = 4 * rg;
    const int oo = og * 4;

    for (int tile = bid; tile < 2048; tile += 768) {
      __syncthreads();           // guard smem reuse across reps/phases
      const size_t pos0 = (size_t)tile * 128;
      const size_t p0 = pos0 + lrow0;
      const int k0 = (int)(p0 & 31), j = (int)(p0 >> 5) & 31,
                i = (int)(p0 >> 10) & 31, b = (int)(p0 >> 15);

      // row-invariant table loads first: latency hides under stage+sync+FMA
      const float4 va3  = *(const float4*)(A3o  + ((size_t)((b * 32 + i) * 32 + j)) * 32 + oo);
      const float4 va13 = *(const float4*)(A13g + (size_t)(b * 32 + j) * 32 + oo);
      const float4 va23 = *(const float4*)(A23g + (size_t)(b * 32 + i) * 32 + oo);
      const float4 va123= *(const float4*)(A123g + (size_t)b * 32 + oo);
      const float4 vbi  = *(const float4*)(bias + oo);

      // stage x tile: 128 rows * 32c = 1024 float4, 4 per thread
      const float4* xp4 = (const float4*)(x + pos0 * 32);
      #pragma unroll
      for (int m = 0; m < 4; ++m) {
        const int q = t + 256 * m;
        const float4 v = xp4[q];
        float* p = xs + (q >> 3) * 33 + 4 * (q & 7);
        p[0] = v.x; p[1] = v.y; p[2] = v.z; p[3] = v.w;
      }
      #pragma unroll
      for (int m = 0; m < 4; ++m) wt[t + 256 * m] = W0t[t + 256 * m];
      __syncthreads();

      float acc[4][4];
      #pragma unroll
      for (int r = 0; r < 4; ++r)
        #pragma unroll
        for (int u = 0; u < 4; ++u) acc[r][u] = 0.f;

      const float4* wt4 = (const float4*)wt;
      #pragma unroll
      for (int c = 0; c < 32; ++c) {
        const float4 w = wt4[c * 8 + og];
        #pragma unroll
        for (int r = 0; r < 4; ++r) {
          const float xv = xs[(lrow0 + r) * 33 + c];
          acc[r][0] += xv * w.x; acc[r][1] += xv * w.y;
          acc[r][2] += xv * w.z; acc[r][3] += xv * w.w;
        }
      }

      float inv[4];
      inv[0] = va3.x + va13.x + va23.x + va123.x + vbi.x;
      inv[1] = va3.y + va13.y + va23.y + va123.y + vbi.y;
      inv[2] = va3.z + va13.z + va23.z + va123.z + vbi.z;
      inv[3] = va3.w + va13.w + va23.w + va123.w + vbi.w;

      #pragma unroll
      for (int r = 0; r < 4; ++r) {
        const int k = k0 + r;
        const float4 vb1 = *(const float4*)(B1 + ((size_t)((b * 32 + j) * 32 + k)) * 32 + oo);
        const float4 vb2 = *(const float4*)(B2 + ((size_t)((b * 32 + i) * 32 + k)) * 32 + oo);
        const float4 v12 = *(const float4*)(A12g + (size_t)(b * 32 + k) * 32 + oo);
        acc[r][0] += inv[0] + vb1.x + vb2.x + v12.x;
        acc[r][1] += inv[1] + vb1.y + vb2.y + v12.y;
        acc[r][2] += inv[2] + vb1.z + vb2.z + v12.z;
        acc[r][3] += inv[3] + vb1.w + vb2.w + v12.w;
      }

      #pragma unroll
      for (int r = 0; r < 4; ++r) {
        *(float4*)(out + (p0 + r) * 32 + oo) =
            make_float4(acc[r][0], acc[r][1], acc[r][2], acc[r][3]);
      }
    }
  }
}

extern "C" void kernel_launch(void* const* d_in, const int* in_sizes, int n_in,
                              void* d_out, int out_size, void* d_ws, size_t ws_size,
                              hipStream_t stream) {
  const float* x    = (const float*)d_in[0];
  const float* W    = (const float*)d_in[1];
  const float* bias = (const float*)d_in[2];
  float* out = (float*)d_out;
  float* ws  = (float*)d_ws;
  float* S1    = ws;                // 262144
  float* S2    = ws + 262144;
  float* S3    = ws + 524288;
  float* B1    = ws + 786432;
  float* B2    = ws + 1048576;
  float* A3o   = ws + 1310720;
  float* W0t   = ws + 1572864;      // 1024
  float* A12g  = ws + 1573888;      // 8192
  float* A13g  = ws + 1582080;      // 8192
  float* A23g  = ws + 1590272;      // 8192
  float* A123g = ws + 1598464;      // 256
  unsigned* barrier_cnt = (unsigned*)(ws + 1598720);

  hipMemsetAsync(barrier_cnt, 0, sizeof(unsigned), stream);
  fused_kernel<<<768, 256, 0, stream>>>(x, W, bias, S1, S2, S3, B1, B2, A3o,
                                        A12g, A13g, A23g, A123g, W0t,
                                        barrier_cnt, out);
}

// Round 8
// 109.246 us; speedup vs baseline: 4.4630x; 4.4630x over previous
//
#include <hip/hip_runtime.h>

// x: [8, 32, 32, 32, 32] fp32.  Flat = b*2^20 + i*32768 + j*1024 + k*32 + c
// W: [32, 256] row-major (o, 8 sections). Sections:
//   0:x 1:mean_i 2:mean_j 3:mean_k 4:mean_ij 5:mean_ik 6:mean_jk 7:mean_ijk
// out[b,i,j,k,o] = W0.x + B1[b,j,k,o] + B2[b,i,k,o] + A3[b,i,j,o]
//                + A12[b,k,o] + A13[b,j,o] + A23[b,i,o] + A123[b,o] + bias[o]
// R14: revert to R4 structure (107.4us best). ONE variable: reduce_kernel
// parallelism 512->1024 blocks (4/CU). Each seg0 unit splits i-range in
// half (partial S1 halves); each segA unit splits jt-range in half (partial
// S2 halves; S3 rows split naturally). mid/pool dual-read the halves and
// add (+3MB L2-resident reads). mid GEMM + final byte-identical to R4.
// R7 evidence: manual grid-barrier fusion = 460us (spin-bound) - dead end.

static __device__ __forceinline__ float4 f4add(float4 a, float4 b) {
  a.x += b.x; a.y += b.y; a.z += b.z; a.w += b.w; return a;
}

// grid 1024: blocks 0..511 seg0 (b, a=j, h = i-half); 512..1023 segA
// (b, a=i, h = jt-half).
__global__ __launch_bounds__(256) void reduce_kernel(
    const float* __restrict__ x,
    float* __restrict__ S1h0, float* __restrict__ S1h1,
    float* __restrict__ S2h0, float* __restrict__ S2h1,
    float* __restrict__ S3) {
  const int t = threadIdx.x;
  if (blockIdx.x < 512) {
    // seg0: S1h[h][b,a,k,c] = sum_{i in [16h,16h+16)} x[b,i,a,k,c]
    const int b = blockIdx.x >> 6, rem = blockIdx.x & 63;
    const int a = rem >> 1, h = rem & 1;
    const float* base = x + ((size_t)b << 20) + a * 1024 + 4 * t + (h << 4) * 32768;
    float4 acc = make_float4(0.f, 0.f, 0.f, 0.f);
    #pragma unroll
    for (int i = 0; i < 16; ++i) acc = f4add(acc, *(const float4*)(base + i * 32768));
    float* S1h = h ? S1h1 : S1h0;
    ((float4*)(S1h + (size_t)(b * 32 + a) * 1024))[t] = acc;
  } else {
    // segA: block (b, i=a, h): stream 2 jt-tiles of slab x[b,a,:,:,:]
    __shared__ float sT[8 * 1028];   // 8 j-rows of [k,c] (1024) + 4 pad
    const int idx = blockIdx.x - 512;
    const int b = idx >> 6, rem = idx & 63;
    const int a = rem >> 1, h = rem & 1;
    const float* slab = x + ((size_t)b << 20) + a * 32768;
    float4 accS2 = make_float4(0.f, 0.f, 0.f, 0.f);
    const int jl = t >> 5, cc = t & 31;      // S3 role: (j_loc, c)
    float* s3row = S3 + (size_t)(b * 32 + a) * 1024;

    for (int jt = 2 * h; jt < 2 * h + 2; ++jt) {
      // load 8 KB tile (j = 8*jt .. +7), fully coalesced float4
      const float4* src4 = (const float4*)(slab + jt * 8192);
      #pragma unroll
      for (int m = 0; m < 8; ++m) {
        const int q = t + 256 * m;           // float4 idx in tile
        const float4 v = src4[q];
        float* p = sT + (q >> 8) * 1028 + 4 * (q & 255);
        p[0] = v.x; p[1] = v.y; p[2] = v.z; p[3] = v.w;
      }
      __syncthreads();
      // S2 accumulate: thread owns (k,c) quad at 4t
      #pragma unroll
      for (int j = 0; j < 8; ++j)
        accS2 = f4add(accS2, *(const float4*)(sT + j * 1028 + 4 * t));
      // S3: thread (jl, cc) sums over k; banks 2-way, free
      float s3 = 0.f;
      #pragma unroll
      for (int k = 0; k < 32; ++k) s3 += sT[jl * 1028 + k * 32 + cc];
      s3row[jt * 256 + t] = s3;              // j = 8*jt + jl, coalesced
      __syncthreads();
    }
    float* S2h = h ? S2h1 : S2h0;
    ((float4*)(S2h + (size_t)(b * 32 + a) * 1024))[t] = accS2;
  }
}

// Merged: blocks 0..95 = three [8192x32]x[32x32] GEMMs (B1,B2,A3, scaled 1/32)
//         with dual-half source merge; blocks 96..119 = second-level pools.
__global__ __launch_bounds__(256) void mid_kernel(
    const float* __restrict__ S1h0, const float* __restrict__ S1h1,
    const float* __restrict__ S2h0, const float* __restrict__ S2h1,
    const float* __restrict__ S3, const float* __restrict__ W,
    float* __restrict__ B1, float* __restrict__ B2, float* __restrict__ A3o,
    float* __restrict__ A12g, float* __restrict__ A13g,
    float* __restrict__ A23g, float* __restrict__ A123g,
    float* __restrict__ W0t) {
  __shared__ float smem[9472];
  const int t = threadIdx.x;
  if (blockIdx.x < 96) {
    float* xs = smem;            // [256][33]
    float* wt = smem + 8448;     // W section seg+1 transposed [c*32+o]
    const int seg = blockIdx.x >> 5;
    const int r0 = (blockIdx.x & 31) * 256;
    const float* srcA = (seg == 0) ? S1h0 : (seg == 1) ? S2h0 : S3;
    const float* srcB = (seg == 0) ? S1h1 : (seg == 1) ? S2h1 : S3;
    const bool dual = (seg < 2);
    float* dst = (seg == 0) ? B1 : (seg == 1) ? B2 : A3o;

    const float4* spA = (const float4*)(srcA + (size_t)r0 * 32);
    const float4* spB = (const float4*)(srcB + (size_t)r0 * 32);
    #pragma unroll
    for (int m = 0; m < 8; ++m) {
      const int q = t + 256 * m;
      float4 v = spA[q];
      if (dual) v = f4add(v, spB[q]);
      float* p = xs + (q >> 3) * 33 + 4 * (q & 7);
      p[0] = v.x; p[1] = v.y; p[2] = v.z; p[3] = v.w;
    }
    #pragma unroll
    for (int m = 0; m < 4; ++m) {
      const int e = t + 256 * m;
      wt[e] = W[(e & 31) * 256 + (seg + 1) * 32 + (e >> 5)];
    }
    if (blockIdx.x == 0) {
      #pragma unroll
      for (int m = 0; m < 4; ++m) {
        const int e = t + 256 * m;
        W0t[e] = W[(e & 31) * 256 + (e >> 5)];   // W0t[c*32+o]
      }
    }
    __syncthreads();

    float acc[32];
    #pragma unroll
    for (int o = 0; o < 32; ++o) acc[o] = 0.f;
    const float4* wt4 = (const float4*)wt;
    #pragma unroll
    for (int c = 0; c < 32; ++c) {
      const float xv = xs[t * 33 + c];
      #pragma unroll
      for (int o4 = 0; o4 < 8; ++o4) {
        const float4 w = wt4[c * 8 + o4];
        acc[o4 * 4 + 0] += xv * w.x;
        acc[o4 * 4 + 1] += xv * w.y;
        acc[o4 * 4 + 2] += xv * w.z;
        acc[o4 * 4 + 3] += xv * w.w;
      }
    }
    __syncthreads();
    #pragma unroll
    for (int o = 0; o < 32; ++o) xs[t * 33 + o] = acc[o] * (1.f / 32.f);
    __syncthreads();
    float* op = dst + (size_t)r0 * 32;
    #pragma unroll
    for (int m = 0; m < 32; ++m) {
      const int f = t + 256 * m;
      op[f] = xs[(f >> 5) * 33 + (f & 31)];
    }
  } else {
    // pool: blk = seg*8 + b. All segs read a dual-half source pair.
    const int blk = blockIdx.x - 96;
    const int seg = blk >> 3, b = blk & 7;
    float* sBuf  = smem;          // [32][32] second-level sums
    float* sW    = smem + 1024;   // section 4+seg transposed [c*32+o]
    float* sW7   = smem + 2048;   // section 7 transposed
    float* sS123 = smem + 3072;   // [32]
    const int sec = 4 + seg;

    #pragma unroll
    for (int m = 0; m < 4; ++m) {
      const int e = t + 256 * m, c = e >> 5, o = e & 31;
      sW[e] = W[o * 256 + sec * 32 + c];
      if (seg == 0) sW7[e] = W[o * 256 + 7 * 32 + c];
    }
    const float* SbA = ((seg == 2) ? S2h0 : S1h0) + (size_t)b * 32768;
    const float* SbB = ((seg == 2) ? S2h1 : S1h1) + (size_t)b * 32768;
    #pragma unroll
    for (int m = 0; m < 4; ++m) {
      const int e = t + 256 * m, a = e >> 5, c = e & 31;
      float s = 0.f;
      if (seg == 0) {            // S12[k=a,c] = sum_j S1[b,j,a,c]
        for (int j = 0; j < 32; ++j)
          s += SbA[j * 1024 + a * 32 + c] + SbB[j * 1024 + a * 32 + c];
      } else {                   // S13/S23[(j|i)=a,c] = sum_k
        for (int k = 0; k < 32; ++k)
          s += SbA[a * 1024 + k * 32 + c] + SbB[a * 1024 + k * 32 + c];
      }
      sBuf[e] = s;
    }
    __syncthreads();
    if (seg == 0 && t < 32) {
      float s = 0.f;
      for (int k = 0; k < 32; ++k) s += sBuf[k * 32 + t];
      sS123[t] = s;
    }
    __syncthreads();
    float* Ag = (seg == 0) ? A12g : (seg == 1) ? A13g : A23g;
    #pragma unroll
    for (int m = 0; m < 4; ++m) {
      const int e = t + 256 * m, a = e >> 5, o = e & 31;
      float s = 0.f;
      #pragma unroll
      for (int c = 0; c < 32; ++c) s += sW[c * 32 + o] * sBuf[a * 32 + c];
      Ag[b * 1024 + e] = s * (1.f / 1024.f);
    }
    if (seg == 0 && t < 32) {
      float s = 0.f;
      #pragma unroll
      for (int c = 0; c < 32; ++c) s += sW7[c * 32 + t] * sS123[c];
      A123g[b * 32 + t] = s * (1.f / 32768.f);
    }
  }
}

// 128 rows/block, 2048 blocks. LDS = 128*33 + 1024 floats = 20.9 KB ->
// 7 blocks/CU. Thread = (rg=t>>3: 4 rows, og=t&7: 4 outs). (R4 verbatim.)
__global__ __launch_bounds__(256) void final_kernel(
    const float* __restrict__ x, const float* __restrict__ W0t,
    const float* __restrict__ B1, const float* __restrict__ B2,
    const float* __restrict__ A3o, const float* __restrict__ A12g,
    const float* __restrict__ A13g, const float* __restrict__ A23g,
    const float* __restrict__ A123g, const float* __restrict__ bias,
    float* __restrict__ out) {
  __shared__ float xs[128 * 33];
  __shared__ float wt[1024];     // W0 transposed [c*32+o]
  const int t = threadIdx.x;
  const size_t pos0 = (size_t)blockIdx.x * 128;

  const int rg = t >> 3, og = t & 7;
  const int lrow0 = 4 * rg;
  const size_t p0 = pos0 + lrow0;
  const int k0 = (int)(p0 & 31), j = (int)(p0 >> 5) & 31,
            i = (int)(p0 >> 10) & 31, b = (int)(p0 >> 15);
  const int oo = og * 4;

  // issue row-invariant table loads first: latency hides under stage+sync+FMA
  const float4 va3  = *(const float4*)(A3o  + ((size_t)((b * 32 + i) * 32 + j)) * 32 + oo);
  const float4 va13 = *(const float4*)(A13g + (size_t)(b * 32 + j) * 32 + oo);
  const float4 va23 = *(const float4*)(A23g + (size_t)(b * 32 + i) * 32 + oo);
  const float4 va123= *(const float4*)(A123g + (size_t)b * 32 + oo);
  const float4 vbi  = *(const float4*)(bias + oo);

  // stage x tile: 128 rows * 32c = 1024 float4, 4 per thread
  const float4* xp4 = (const float4*)(x + pos0 * 32);
  #pragma unroll
  for (int m = 0; m < 4; ++m) {
    const int q = t + 256 * m;
    const float4 v = xp4[q];
    float* p = xs + (q >> 3) * 33 + 4 * (q & 7);
    p[0] = v.x; p[1] = v.y; p[2] = v.z; p[3] = v.w;
  }
  #pragma unroll
  for (int m = 0; m < 4; ++m) wt[t + 256 * m] = W0t[t + 256 * m];
  __syncthreads();

  float acc[4][4];
  #pragma unroll
  for (int r = 0; r < 4; ++r)
    #pragma unroll
    for (int u = 0; u < 4; ++u) acc[r][u] = 0.f;

  const float4* wt4 = (const float4*)wt;
  #pragma unroll
  for (int c = 0; c < 32; ++c) {
    const float4 w = wt4[c * 8 + og];
    #pragma unroll
    for (int r = 0; r < 4; ++r) {
      const float xv = xs[(lrow0 + r) * 33 + c];
      acc[r][0] += xv * w.x; acc[r][1] += xv * w.y;
      acc[r][2] += xv * w.z; acc[r][3] += xv * w.w;
    }
  }

  float inv[4];
  inv[0] = va3.x + va13.x + va23.x + va123.x + vbi.x;
  inv[1] = va3.y + va13.y + va23.y + va123.y + vbi.y;
  inv[2] = va3.z + va13.z + va23.z + va123.z + vbi.z;
  inv[3] = va3.w + va13.w + va23.w + va123.w + vbi.w;

  #pragma unroll
  for (int r = 0; r < 4; ++r) {
    const int k = k0 + r;
    const float4 vb1 = *(const float4*)(B1 + ((size_t)((b * 32 + j) * 32 + k)) * 32 + oo);
    const float4 vb2 = *(const float4*)(B2 + ((size_t)((b * 32 + i) * 32 + k)) * 32 + oo);
    const float4 v12 = *(const float4*)(A12g + (size_t)(b * 32 + k) * 32 + oo);
    acc[r][0] += inv[0] + vb1.x + vb2.x + v12.x;
    acc[r][1] += inv[1] + vb1.y + vb2.y + v12.y;
    acc[r][2] += inv[2] + vb1.z + vb2.z + v12.z;
    acc[r][3] += inv[3] + vb1.w + vb2.w + v12.w;
  }

  #pragma unroll
  for (int r = 0; r < 4; ++r) {
    *(float4*)(out + (p0 + r) * 32 + oo) =
        make_float4(acc[r][0], acc[r][1], acc[r][2], acc[r][3]);
  }
}

extern "C" void kernel_launch(void* const* d_in, const int* in_sizes, int n_in,
                              void* d_out, int out_size, void* d_ws, size_t ws_size,
                              hipStream_t stream) {
  const float* x    = (const float*)d_in[0];
  const float* W    = (const float*)d_in[1];
  const float* bias = (const float*)d_in[2];
  float* out = (float*)d_out;
  float* ws  = (float*)d_ws;
  float* S1h0  = ws;                 // 262144 each
  float* S1h1  = ws + 262144;
  float* S2h0  = ws + 524288;
  float* S2h1  = ws + 786432;
  float* S3    = ws + 1048576;
  float* B1    = ws + 1310720;
  float* B2    = ws + 1572864;
  float* A3o   = ws + 1835008;
  float* W0t   = ws + 2097152;       // 1024
  float* A12g  = ws + 2098176;       // 8192
  float* A13g  = ws + 2106368;       // 8192
  float* A23g  = ws + 2114560;       // 8192
  float* A123g = ws + 2122752;       // 256

  reduce_kernel<<<1024, 256, 0, stream>>>(x, S1h0, S1h1, S2h0, S2h1, S3);
  mid_kernel<<<120, 256, 0, stream>>>(S1h0, S1h1, S2h0, S2h1, S3, W,
                                      B1, B2, A3o, A12g, A13g, A23g, A123g, W0t);
  final_kernel<<<2048, 256, 0, stream>>>(x, W0t, B1, B2, A3o, A12g, A13g,
                                         A23g, A123g, bias, out);
}